// Round 4
// baseline (337.005 us; speedup 1.0000x reference)
//
#include <hip/hip_runtime.h>
#include <cstdint>
#include <cstddef>

typedef __bf16 bfloat;
typedef __bf16 bf16x8 __attribute__((ext_vector_type(8)));
typedef __bf16 bf16x4 __attribute__((ext_vector_type(4)));
typedef float  f32x4  __attribute__((ext_vector_type(4)));

static constexpr int D  = 1024;
static constexpr int S  = 2048;
static constexpr int B  = 2;
static constexpr int H  = 16;
static constexpr int DH = 64;
static constexpr int M  = B * S;
static constexpr int WMAT_N = 1024 * 1024;

#define MFMA_BF16(a, b, c) __builtin_amdgcn_mfma_f32_16x16x32_bf16((a), (b), (c), 0, 0, 0)

__device__ __forceinline__ void gl_lds16(const void* g, void* l) {
  __builtin_amdgcn_global_load_lds(
      (const __attribute__((address_space(1))) void*)g,
      (__attribute__((address_space(3))) void*)l, 16, 0, 0);
}

// 16-lane max reduction on the VALU via DPP (no LDS-pipe traffic).
// quad_perm(1,0,3,2)=0xB1; quad_perm(2,3,0,1)=0x4E; half_mirror=0x141; mirror=0x140
__device__ __forceinline__ float dpp_max16(float x) {
  float y;
  y = __builtin_bit_cast(float, __builtin_amdgcn_update_dpp(
          0, __builtin_bit_cast(int, x), 0xB1, 0xF, 0xF, true));
  x = fmaxf(x, y);
  y = __builtin_bit_cast(float, __builtin_amdgcn_update_dpp(
          0, __builtin_bit_cast(int, x), 0x4E, 0xF, 0xF, true));
  x = fmaxf(x, y);
  y = __builtin_bit_cast(float, __builtin_amdgcn_update_dpp(
          0, __builtin_bit_cast(int, x), 0x141, 0xF, 0xF, true));
  x = fmaxf(x, y);
  y = __builtin_bit_cast(float, __builtin_amdgcn_update_dpp(
          0, __builtin_bit_cast(int, x), 0x140, 0xF, 0xF, true));
  x = fmaxf(x, y);
  return x;
}

// ---------------- abs-sum reduce in f64 ----------------
__global__ void absum_kernel(const float* __restrict__ w0, const float* __restrict__ w1,
                             const float* __restrict__ w2, const float* __restrict__ w3,
                             double* __restrict__ sums) {
  int z = blockIdx.y;
  const float* w = (z == 0) ? w0 : (z == 1) ? w1 : (z == 2) ? w2 : w3;
  const float4* w4 = (const float4*)w;
  double s = 0.0;
  for (int i = blockIdx.x * blockDim.x + threadIdx.x; i < (WMAT_N / 4);
       i += gridDim.x * blockDim.x) {
    float4 v = w4[i];
    s += (double)fabsf(v.x) + (double)fabsf(v.y) + (double)fabsf(v.z) + (double)fabsf(v.w);
  }
  for (int off = 1; off < 64; off <<= 1) s += __shfl_xor(s, off, 64);
  __shared__ double ps[4];
  if ((threadIdx.x & 63) == 0) ps[threadIdx.x >> 6] = s;
  __syncthreads();
  if (threadIdx.x == 0) atomicAdd(&sums[z], ps[0] + ps[1] + ps[2] + ps[3]);
}

// ---------------- ternarize -> bf16 ----------------
__global__ void tern_kernel(const float* __restrict__ w0, const float* __restrict__ w1,
                            const float* __restrict__ w2, const float* __restrict__ w3,
                            bfloat* __restrict__ o0, bfloat* __restrict__ o1,
                            bfloat* __restrict__ o2, bfloat* __restrict__ o3,
                            const double* __restrict__ sums) {
  int z = blockIdx.y;
  const float* w = (z == 0) ? w0 : (z == 1) ? w1 : (z == 2) ? w2 : w3;
  bfloat* o = (z == 0) ? o0 : (z == 1) ? o1 : (z == 2) ? o2 : o3;
  double thr = sums[z] * (1.0 / (double)WMAT_N);
  const float4* w4 = (const float4*)w;
  for (int i = blockIdx.x * blockDim.x + threadIdx.x; i < (WMAT_N / 4);
       i += gridDim.x * blockDim.x) {
    float4 v = w4[i];
    bf16x4 r;
    r[0] = (bfloat)(((double)fabsf(v.x) > thr) ? (v.x > 0.f ? 1.f : -1.f) : 0.f);
    r[1] = (bfloat)(((double)fabsf(v.y) > thr) ? (v.y > 0.f ? 1.f : -1.f) : 0.f);
    r[2] = (bfloat)(((double)fabsf(v.z) > thr) ? (v.z > 0.f ? 1.f : -1.f) : 0.f);
    r[3] = (bfloat)(((double)fabsf(v.w) > thr) ? (v.w > 0.f ? 1.f : -1.f) : 0.f);
    *(bf16x4*)&o[(size_t)i * 4] = r;
  }
}

// ------------- fp32 -> bf16 hi (+ lo residual) for q,k,v in one launch -----
__global__ void splitcvt3_kernel(const float* __restrict__ qx, const float* __restrict__ kx,
                                 const float* __restrict__ vx, bfloat* __restrict__ qhi,
                                 bfloat* __restrict__ qlo, bfloat* __restrict__ khi,
                                 bfloat* __restrict__ klo, bfloat* __restrict__ vhi) {
  int z = blockIdx.y;
  const float* x = (z == 0) ? qx : (z == 1) ? kx : vx;
  bfloat* hi = (z == 0) ? qhi : (z == 1) ? khi : vhi;
  bfloat* lo = (z == 0) ? qlo : (z == 1) ? klo : nullptr;
  const int n4 = M * D / 4;
  const float4* x4 = (const float4*)x;
  for (int i = blockIdx.x * blockDim.x + threadIdx.x; i < n4; i += gridDim.x * blockDim.x) {
    float4 v = x4[i];
    bf16x4 h;
    h[0] = (bfloat)v.x; h[1] = (bfloat)v.y; h[2] = (bfloat)v.z; h[3] = (bfloat)v.w;
    *(bf16x4*)&hi[(size_t)i * 4] = h;
    if (z < 2) {
      bf16x4 l;
      l[0] = (bfloat)(v.x - (float)h[0]);
      l[1] = (bfloat)(v.y - (float)h[1]);
      l[2] = (bfloat)(v.z - (float)h[2]);
      l[3] = (bfloat)(v.w - (float)h[3]);
      *(bf16x4*)&lo[(size_t)i * 4] = l;
    }
  }
}

// --------- V transpose: [B*S][D] -> [B][D][S] ---------
__global__ __launch_bounds__(256) void transpose_v(const bfloat* __restrict__ in,
                                                   bfloat* __restrict__ out) {
  __shared__ __align__(16) bfloat T[64 * 72];
  const int t = threadIdx.x;
  const int s0 = blockIdx.x * 64, n0 = blockIdx.y * 64, b = blockIdx.z;
#pragma unroll
  for (int p = 0; p < 2; p++) {
    int e = t * 8 + p * 2048;
    int r = e >> 6, cc = e & 63;
    bf16x8 v = *(const bf16x8*)&in[(size_t)(b * S + s0 + r) * D + n0 + cc];
#pragma unroll
    for (int j = 0; j < 8; j++) T[(cc + j) * 72 + r] = v[j];
  }
  __syncthreads();
#pragma unroll
  for (int p = 0; p < 2; p++) {
    int e = t * 8 + p * 2048;
    int f = e >> 6, cc = e & 63;
    bf16x8 v = *(const bf16x8*)&T[f * 72 + cc];
    *(bf16x8*)&out[(size_t)b * D * S + (size_t)(n0 + f) * S + s0 + cc] = v;
  }
}

// -------- fused q/k/v projection: blockIdx.z selects matrix ---------------
__global__ __launch_bounds__(256) void qkv_gemm(
    const bfloat* __restrict__ xqh, const bfloat* __restrict__ xql,
    const bfloat* __restrict__ xkh, const bfloat* __restrict__ xkl,
    const bfloat* __restrict__ xvh, const bfloat* __restrict__ wqt,
    const bfloat* __restrict__ wkt, const bfloat* __restrict__ wvt,
    bfloat* __restrict__ qmh, bfloat* __restrict__ qml,
    bfloat* __restrict__ kmh, bfloat* __restrict__ kml, bfloat* __restrict__ vmm) {
  constexpr int K = D;
  constexpr int N = D;
  __shared__ __align__(16) bfloat As0[128 * 32];
  __shared__ __align__(16) bfloat As1[128 * 32];
  __shared__ __align__(16) bfloat Ws[128 * 32];

  const int z = blockIdx.z;
  const bfloat *A0, *A1 = nullptr, *Wm;
  bfloat *Oh, *Ol = nullptr;
  float scale = 1.f;
  bool split;
  if (z == 0) {
    A0 = xqh; A1 = xql; Wm = wqt; Oh = qmh; Ol = qml;
    scale = 0.18033688f;  // 1/sqrt(64) * log2(e), folded out of flash
    split = true;
  } else if (z == 1) {
    A0 = xkh; A1 = xkl; Wm = wkt; Oh = kmh; Ol = kml; split = true;
  } else {
    A0 = xvh; Wm = wvt; Oh = vmm; split = false;
  }

  const int t = threadIdx.x;
  const int w = t >> 6, lane = t & 63;
  const int quad = lane >> 4, l16 = lane & 15;
  const int wm = w >> 1, wn = w & 1;
  const int m0 = blockIdx.y * 128, n0 = blockIdx.x * 128;

  f32x4 acc[4][4] = {};

  const int sr = t >> 2;
  const int sc = (t & 3) * 8;

  const bfloat* pA0a = A0 + (size_t)(m0 + sr) * K + sc;
  const bfloat* pA0b = A0 + (size_t)(m0 + 64 + sr) * K + sc;
  const bfloat* pA1a = split ? A1 + (size_t)(m0 + sr) * K + sc : nullptr;
  const bfloat* pA1b = split ? A1 + (size_t)(m0 + 64 + sr) * K + sc : nullptr;
  const bfloat* pWa = Wm + (size_t)(n0 + sr) * K + sc;
  const bfloat* pWb = Wm + (size_t)(n0 + 64 + sr) * K + sc;

  for (int kk = 0; kk < K; kk += 32) {
    gl_lds16(pA0a + kk, As0 + w * 512);
    gl_lds16(pA0b + kk, As0 + 2048 + w * 512);
    if (split) {
      gl_lds16(pA1a + kk, As1 + w * 512);
      gl_lds16(pA1b + kk, As1 + 2048 + w * 512);
    }
    gl_lds16(pWa + kk, Ws + w * 512);
    gl_lds16(pWb + kk, Ws + 2048 + w * 512);
    __syncthreads();

    bf16x8 bfrag[4], afrag[4];
#pragma unroll
    for (int nt = 0; nt < 4; nt++)
      bfrag[nt] = *(const bf16x8*)&Ws[(wn * 64 + nt * 16 + l16) * 32 + quad * 8];
#pragma unroll
    for (int mt = 0; mt < 4; mt++)
      afrag[mt] = *(const bf16x8*)&As0[(wm * 64 + mt * 16 + l16) * 32 + quad * 8];
#pragma unroll
    for (int mt = 0; mt < 4; mt++)
#pragma unroll
      for (int nt = 0; nt < 4; nt++)
        acc[mt][nt] = MFMA_BF16(afrag[mt], bfrag[nt], acc[mt][nt]);
    if (split) {
#pragma unroll
      for (int mt = 0; mt < 4; mt++)
        afrag[mt] = *(const bf16x8*)&As1[(wm * 64 + mt * 16 + l16) * 32 + quad * 8];
#pragma unroll
      for (int mt = 0; mt < 4; mt++)
#pragma unroll
        for (int nt = 0; nt < 4; nt++)
          acc[mt][nt] = MFMA_BF16(afrag[mt], bfrag[nt], acc[mt][nt]);
    }
    __syncthreads();
  }

#pragma unroll
  for (int mt = 0; mt < 4; mt++) {
#pragma unroll
    for (int nt = 0; nt < 4; nt++) {
      const int row = m0 + wm * 64 + mt * 16 + quad * 4;
      const int col = n0 + wn * 64 + nt * 16 + l16;
#pragma unroll
      for (int rg = 0; rg < 4; rg++) {
        float vv = acc[mt][nt][rg] * scale;
        size_t idx = (size_t)(row + rg) * N + col;
        bfloat hh = (bfloat)vv;
        Oh[idx] = hh;
        if (split) Ol[idx] = (bfloat)(vv - (float)hh);
      }
    }
  }
}

// -------- W_O GEMM: 128x64 tile, grid (16,32)=512 blocks = 2/CU, fp32 out --
__global__ __launch_bounds__(256) void gemm_wo(const bfloat* __restrict__ A,
                                               const bfloat* __restrict__ Wm,
                                               float* __restrict__ Cf) {
  constexpr int K = D;
  constexpr int N = D;
  __shared__ __align__(16) bfloat As[128 * 32];
  __shared__ __align__(16) bfloat Ws[64 * 32];

  const int t = threadIdx.x;
  const int w = t >> 6, lane = t & 63;
  const int quad = lane >> 4, l16 = lane & 15;
  const int wm = w >> 1, wn = w & 1;
  const int m0 = blockIdx.y * 128, n0 = blockIdx.x * 64;

  f32x4 acc[4][2] = {};

  const int sr = t >> 2;
  const int sc = (t & 3) * 8;
  const bfloat* pAa = A + (size_t)(m0 + sr) * K + sc;
  const bfloat* pAb = A + (size_t)(m0 + 64 + sr) * K + sc;
  const bfloat* pW = Wm + (size_t)(n0 + sr) * K + sc;

  for (int kk = 0; kk < K; kk += 32) {
    gl_lds16(pAa + kk, As + w * 512);
    gl_lds16(pAb + kk, As + 2048 + w * 512);
    gl_lds16(pW + kk, Ws + w * 512);
    __syncthreads();

    bf16x8 bfrag[2], afrag[4];
#pragma unroll
    for (int nt = 0; nt < 2; nt++)
      bfrag[nt] = *(const bf16x8*)&Ws[(wn * 32 + nt * 16 + l16) * 32 + quad * 8];
#pragma unroll
    for (int mt = 0; mt < 4; mt++)
      afrag[mt] = *(const bf16x8*)&As[(wm * 64 + mt * 16 + l16) * 32 + quad * 8];
#pragma unroll
    for (int mt = 0; mt < 4; mt++)
#pragma unroll
      for (int nt = 0; nt < 2; nt++)
        acc[mt][nt] = MFMA_BF16(afrag[mt], bfrag[nt], acc[mt][nt]);
    __syncthreads();
  }

#pragma unroll
  for (int mt = 0; mt < 4; mt++) {
#pragma unroll
    for (int nt = 0; nt < 2; nt++) {
      const int row = m0 + wm * 64 + mt * 16 + quad * 4;
      const int col = n0 + wn * 32 + nt * 16 + l16;
#pragma unroll
      for (int rg = 0; rg < 4; rg++) Cf[(size_t)(row + rg) * N + col] = acc[mt][nt][rg];
    }
  }
}

// ---------------- flash attention v4 ----------------
// 128 Q rows per block (32/wave, 2 row-frags in registers) -> shared K/V LDS
// reads amortize over 2x MFMA work. DPP max-reduce (VALU, no LDS). l_i via
// MFMA against a register-constant ones fragment.
__global__ __launch_bounds__(256) void flash_kernel(
    const bfloat* __restrict__ qh, const bfloat* __restrict__ ql,
    const bfloat* __restrict__ kh, const bfloat* __restrict__ kl,
    const bfloat* __restrict__ vt, bfloat* __restrict__ outp) {
  __shared__ __align__(16) bfloat Kh[64 * 64];
  __shared__ __align__(16) bfloat Kl[64 * 64];
  __shared__ __align__(16) bfloat Vt[64 * 64];
  __shared__ __align__(16) bfloat Pm[128 * 64];

  const int t = threadIdx.x;
  const int w = t >> 6, lane = t & 63;
  const int quad = lane >> 4, l16 = lane & 15;
  const int b = blockIdx.z, h = blockIdx.y;
  const int q0 = blockIdx.x * 128;
  const size_t base = (size_t)b * S * D + (size_t)h * DH;
  const size_t vbase = (size_t)b * D * S + (size_t)h * DH * S;

  const int ssr = lane >> 3;
  const int spc = lane & 7;

  bf16x8 ones;
#pragma unroll
  for (int j = 0; j < 8; j++) ones[j] = (bfloat)1.f;

  // ---- prologue: Q hi then Q lo staged through Kh(rows 0-63)+Kl(64-127) ----
  bf16x8 ah[2][2], al[2][2];  // [row-tile][s2]
#pragma unroll
  for (int phase = 0; phase < 2; phase++) {
    const bfloat* src = phase ? ql : qh;
#pragma unroll
    for (int g = 0; g < 4; g++) {
      int r = w * 32 + g * 8 + ssr;  // 0..127, wave-uniform base
      int c = spc ^ (r & 7);
      bfloat* dst = (r < 64) ? (Kh + (w * 32 + g * 8) * 64)
                             : (Kl + (w * 32 + g * 8 - 64) * 64);
      gl_lds16(src + base + (size_t)(q0 + r) * D + c * 8, dst);
    }
    __syncthreads();
#pragma unroll
    for (int rt = 0; rt < 2; rt++) {
      int row = w * 32 + rt * 16 + l16;  // 0..127
      const bfloat* buf = (row < 64) ? Kh : Kl;
      int brow = row & 63;
#pragma unroll
      for (int s2 = 0; s2 < 2; s2++) {
        bf16x8 v = *(const bf16x8*)&buf[brow * 64 + (((s2 * 4 + quad) ^ (row & 7)) * 8)];
        if (phase) al[rt][s2] = v; else ah[rt][s2] = v;
      }
    }
    __syncthreads();  // frag reads done before next phase / first K staging
  }

  f32x4 Oa[2][4] = {};
  f32x4 La[2] = {};
  float m_i[2][4];
#pragma unroll
  for (int rt = 0; rt < 2; rt++)
#pragma unroll
    for (int i = 0; i < 4; i++) m_i[rt][i] = -3.0e38f;

  for (int k0 = 0; k0 < S; k0 += 64) {
#pragma unroll
    for (int g = 0; g < 2; g++) {
      int r = w * 16 + g * 8 + ssr;
      int c = spc ^ (r & 7);
      int lo = (w * 16 + g * 8) * 64;
      gl_lds16(kh + base + (size_t)(k0 + r) * D + c * 8, Kh + lo);
      gl_lds16(kl + base + (size_t)(k0 + r) * D + c * 8, Kl + lo);
      gl_lds16(vt + vbase + (size_t)r * S + k0 + c * 8, Vt + lo);
    }
    __syncthreads();

    // S = Qh*Kh + Ql*Kh + Qh*Kl (pre-scaled, log2 domain)
    f32x4 sf[2][4];
#pragma unroll
    for (int nt = 0; nt < 4; nt++) {
      f32x4 a0 = {}, a1 = {};
      int row = nt * 16 + l16;
#pragma unroll
      for (int s2 = 0; s2 < 2; s2++) {
        bf16x8 bh = *(const bf16x8*)&Kh[row * 64 + (((s2 * 4 + quad) ^ (row & 7)) * 8)];
        bf16x8 bl = *(const bf16x8*)&Kl[row * 64 + (((s2 * 4 + quad) ^ (row & 7)) * 8)];
        a0 = MFMA_BF16(ah[0][s2], bh, a0);
        a0 = MFMA_BF16(al[0][s2], bh, a0);
        a0 = MFMA_BF16(ah[0][s2], bl, a0);
        a1 = MFMA_BF16(ah[1][s2], bh, a1);
        a1 = MFMA_BF16(al[1][s2], bh, a1);
        a1 = MFMA_BF16(ah[1][s2], bl, a1);
      }
      sf[0][nt] = a0;
      sf[1][nt] = a1;
    }

    // online softmax (DPP max over the 16 lanes of each quad)
#pragma unroll
    for (int rt = 0; rt < 2; rt++) {
#pragma unroll
      for (int rg = 0; rg < 4; rg++) {
        float mm = fmaxf(fmaxf(sf[rt][0][rg], sf[rt][1][rg]),
                         fmaxf(sf[rt][2][rg], sf[rt][3][rg]));
        mm = dpp_max16(mm);
        float mnew = fmaxf(m_i[rt][rg], mm);
        float alpha = exp2f(m_i[rt][rg] - mnew);
        m_i[rt][rg] = mnew;
#pragma unroll
        for (int nt = 0; nt < 4; nt++) sf[rt][nt][rg] = exp2f(sf[rt][nt][rg] - mnew);
#pragma unroll
        for (int nt = 0; nt < 4; nt++) Oa[rt][nt][rg] *= alpha;
        La[rt][rg] *= alpha;
      }

      // P: C-layout -> A-layout via wave-private LDS strip (swizzled)
#pragma unroll
      for (int nt = 0; nt < 4; nt++)
#pragma unroll
        for (int rg = 0; rg < 4; rg++) {
          int row = w * 32 + rt * 16 + quad * 4 + rg;
          int col = nt * 16 + l16;
          Pm[row * 64 + (((col >> 3) ^ (row & 7)) * 8) + (col & 7)] =
              (bfloat)sf[rt][nt][rg];
        }
    }

    // O += P @ V ; La += P @ ones  (Pm strip wave-private: no barrier)
#pragma unroll
    for (int s2 = 0; s2 < 2; s2++) {
      int pr0 = w * 32 + l16;
      int pr1 = w * 32 + 16 + l16;
      bf16x8 pa0 = *(const bf16x8*)&Pm[pr0 * 64 + (((s2 * 4 + quad) ^ (pr0 & 7)) * 8)];
      bf16x8 pa1 = *(const bf16x8*)&Pm[pr1 * 64 + (((s2 * 4 + quad) ^ (pr1 & 7)) * 8)];
#pragma unroll
      for (int nt = 0; nt < 4; nt++) {
        int vrow = nt * 16 + l16;
        bf16x8 vb = *(const bf16x8*)&Vt[vrow * 64 + (((s2 * 4 + quad) ^ (vrow & 7)) * 8)];
        Oa[0][nt] = MFMA_BF16(pa0, vb, Oa[0][nt]);
        Oa[1][nt] = MFMA_BF16(pa1, vb, Oa[1][nt]);
      }
      La[0] = MFMA_BF16(pa0, ones, La[0]);
      La[1] = MFMA_BF16(pa1, ones, La[1]);
    }
    __syncthreads();  // frag reads done before next iteration's staging
  }

#pragma unroll
  for (int rt = 0; rt < 2; rt++)
#pragma unroll
    for (int rg = 0; rg < 4; rg++) {
      float inv = 1.0f / La[rt][rg];
#pragma unroll
      for (int nt = 0; nt < 4; nt++) {
        outp[base + (size_t)(q0 + w * 32 + rt * 16 + quad * 4 + rg) * D + nt * 16 + l16] =
            (bfloat)(Oa[rt][nt][rg] * inv);
      }
    }
}

extern "C" void kernel_launch(void* const* d_in, const int* in_sizes, int n_in,
                              void* d_out, int out_size, void* d_ws, size_t ws_size,
                              hipStream_t stream) {
  const float* q_in = (const float*)d_in[0];
  const float* k_in = (const float*)d_in[1];
  const float* v_in = (const float*)d_in[2];
  const float* wq = (const float*)d_in[3];
  const float* wk = (const float*)d_in[4];
  const float* wv = (const float*)d_in[5];
  const float* wo = (const float*)d_in[6];
  float* outp = (float*)d_out;
  char* ws = (char*)d_ws;

  constexpr size_t WBYTES = (size_t)WMAT_N * 2;
  constexpr size_t XBYTES = (size_t)M * D * 2;
  size_t off = 0;
  double* sums = (double*)(ws + off); off += 256;
  bfloat* wqt = (bfloat*)(ws + off); off += WBYTES;
  bfloat* wkt = (bfloat*)(ws + off); off += WBYTES;
  bfloat* wvt = (bfloat*)(ws + off); off += WBYTES;
  bfloat* wot = (bfloat*)(ws + off); off += WBYTES;
  bfloat* xqh = (bfloat*)(ws + off); off += XBYTES;
  bfloat* xql = (bfloat*)(ws + off); off += XBYTES;
  bfloat* xkh = (bfloat*)(ws + off); off += XBYTES;
  bfloat* xkl = (bfloat*)(ws + off); off += XBYTES;
  bfloat* xvh = (bfloat*)(ws + off); off += XBYTES;
  bfloat* qmh = (bfloat*)(ws + off); off += XBYTES;
  bfloat* qml = (bfloat*)(ws + off); off += XBYTES;
  bfloat* kmh = (bfloat*)(ws + off); off += XBYTES;
  bfloat* kml = (bfloat*)(ws + off); off += XBYTES;
  bfloat* vmm = (bfloat*)(ws + off); off += XBYTES;
  bfloat* attn = xqh;  // dead after q projection
  bfloat* vtr = xvh;   // dead after v projection; reused for V^T [B][D][S]

  hipMemsetAsync(sums, 0, 4 * sizeof(double), stream);
  absum_kernel<<<dim3(128, 4), 256, 0, stream>>>(wq, wk, wv, wo, sums);
  tern_kernel<<<dim3(128, 4), 256, 0, stream>>>(wq, wk, wv, wo, wqt, wkt, wvt, wot, sums);
  splitcvt3_kernel<<<dim3(512, 3), 256, 0, stream>>>(q_in, k_in, v_in, xqh, xql, xkh, xkl, xvh);
  qkv_gemm<<<dim3(D / 128, M / 128, 3), 256, 0, stream>>>(
      xqh, xql, xkh, xkl, xvh, wqt, wkt, wvt, qmh, qml, kmh, kml, vmm);
  transpose_v<<<dim3(S / 64, D / 64, B), 256, 0, stream>>>(vmm, vtr);
  flash_kernel<<<dim3(S / 128, H, B), 256, 0, stream>>>(qmh, qml, kmh, kml, vtr, attn);
  gemm_wo<<<dim3(D / 64, M / 128), 256, 0, stream>>>(attn, wot, outp);
}

// Round 5
// 301.876 us; speedup vs baseline: 1.1164x; 1.1164x over previous
//
#include <hip/hip_runtime.h>
#include <cstdint>
#include <cstddef>

typedef __bf16 bfloat;
typedef __bf16 bf16x8 __attribute__((ext_vector_type(8)));
typedef __bf16 bf16x4 __attribute__((ext_vector_type(4)));
typedef float  f32x4  __attribute__((ext_vector_type(4)));

static constexpr int D  = 1024;
static constexpr int S  = 2048;
static constexpr int B  = 2;
static constexpr int H  = 16;
static constexpr int DH = 64;
static constexpr int M  = B * S;
static constexpr int WMAT_N = 1024 * 1024;

#define MFMA_BF16(a, b, c) __builtin_amdgcn_mfma_f32_16x16x32_bf16((a), (b), (c), 0, 0, 0)

__device__ __forceinline__ void gl_lds16(const void* g, void* l) {
  __builtin_amdgcn_global_load_lds(
      (const __attribute__((address_space(1))) void*)g,
      (__attribute__((address_space(3))) void*)l, 16, 0, 0);
}

// ---------------- abs-sum reduce in f64 ----------------
__global__ void absum_kernel(const float* __restrict__ w0, const float* __restrict__ w1,
                             const float* __restrict__ w2, const float* __restrict__ w3,
                             double* __restrict__ sums) {
  int z = blockIdx.y;
  const float* w = (z == 0) ? w0 : (z == 1) ? w1 : (z == 2) ? w2 : w3;
  const float4* w4 = (const float4*)w;
  double s = 0.0;
  for (int i = blockIdx.x * blockDim.x + threadIdx.x; i < (WMAT_N / 4);
       i += gridDim.x * blockDim.x) {
    float4 v = w4[i];
    s += (double)fabsf(v.x) + (double)fabsf(v.y) + (double)fabsf(v.z) + (double)fabsf(v.w);
  }
  for (int off = 1; off < 64; off <<= 1) s += __shfl_xor(s, off, 64);
  __shared__ double ps[4];
  if ((threadIdx.x & 63) == 0) ps[threadIdx.x >> 6] = s;
  __syncthreads();
  if (threadIdx.x == 0) atomicAdd(&sums[z], ps[0] + ps[1] + ps[2] + ps[3]);
}

// ---------------- ternarize -> bf16 ----------------
__global__ void tern_kernel(const float* __restrict__ w0, const float* __restrict__ w1,
                            const float* __restrict__ w2, const float* __restrict__ w3,
                            bfloat* __restrict__ o0, bfloat* __restrict__ o1,
                            bfloat* __restrict__ o2, bfloat* __restrict__ o3,
                            const double* __restrict__ sums) {
  int z = blockIdx.y;
  const float* w = (z == 0) ? w0 : (z == 1) ? w1 : (z == 2) ? w2 : w3;
  bfloat* o = (z == 0) ? o0 : (z == 1) ? o1 : (z == 2) ? o2 : o3;
  double thr = sums[z] * (1.0 / (double)WMAT_N);
  const float4* w4 = (const float4*)w;
  for (int i = blockIdx.x * blockDim.x + threadIdx.x; i < (WMAT_N / 4);
       i += gridDim.x * blockDim.x) {
    float4 v = w4[i];
    bf16x4 r;
    r[0] = (bfloat)(((double)fabsf(v.x) > thr) ? (v.x > 0.f ? 1.f : -1.f) : 0.f);
    r[1] = (bfloat)(((double)fabsf(v.y) > thr) ? (v.y > 0.f ? 1.f : -1.f) : 0.f);
    r[2] = (bfloat)(((double)fabsf(v.z) > thr) ? (v.z > 0.f ? 1.f : -1.f) : 0.f);
    r[3] = (bfloat)(((double)fabsf(v.w) > thr) ? (v.w > 0.f ? 1.f : -1.f) : 0.f);
    *(bf16x4*)&o[(size_t)i * 4] = r;
  }
}

// ------------- fp32 -> bf16 hi (+ lo residual) for q,k,v in one launch -----
__global__ void splitcvt3_kernel(const float* __restrict__ qx, const float* __restrict__ kx,
                                 const float* __restrict__ vx, bfloat* __restrict__ qhi,
                                 bfloat* __restrict__ qlo, bfloat* __restrict__ khi,
                                 bfloat* __restrict__ klo, bfloat* __restrict__ vhi) {
  int z = blockIdx.y;
  const float* x = (z == 0) ? qx : (z == 1) ? kx : vx;
  bfloat* hi = (z == 0) ? qhi : (z == 1) ? khi : vhi;
  bfloat* lo = (z == 0) ? qlo : (z == 1) ? klo : nullptr;
  const int n4 = M * D / 4;
  const float4* x4 = (const float4*)x;
  for (int i = blockIdx.x * blockDim.x + threadIdx.x; i < n4; i += gridDim.x * blockDim.x) {
    float4 v = x4[i];
    bf16x4 h;
    h[0] = (bfloat)v.x; h[1] = (bfloat)v.y; h[2] = (bfloat)v.z; h[3] = (bfloat)v.w;
    *(bf16x4*)&hi[(size_t)i * 4] = h;
    if (z < 2) {
      bf16x4 l;
      l[0] = (bfloat)(v.x - (float)h[0]);
      l[1] = (bfloat)(v.y - (float)h[1]);
      l[2] = (bfloat)(v.z - (float)h[2]);
      l[3] = (bfloat)(v.w - (float)h[3]);
      *(bf16x4*)&lo[(size_t)i * 4] = l;
    }
  }
}

// -------- fused q/k/v projection: blockIdx.z selects matrix ---------------
// v-branch writes V^T [B][D][S] directly (4 consecutive C-rows per lane =
// contiguous tokens -> b64 stores), eliminating the transpose kernel.
__global__ __launch_bounds__(256) void qkv_gemm(
    const bfloat* __restrict__ xqh, const bfloat* __restrict__ xql,
    const bfloat* __restrict__ xkh, const bfloat* __restrict__ xkl,
    const bfloat* __restrict__ xvh, const bfloat* __restrict__ wqt,
    const bfloat* __restrict__ wkt, const bfloat* __restrict__ wvt,
    bfloat* __restrict__ qmh, bfloat* __restrict__ qml,
    bfloat* __restrict__ kmh, bfloat* __restrict__ kml, bfloat* __restrict__ vtr) {
  constexpr int K = D;
  constexpr int N = D;
  __shared__ __align__(16) bfloat As0[128 * 32];
  __shared__ __align__(16) bfloat As1[128 * 32];
  __shared__ __align__(16) bfloat Ws[128 * 32];

  const int z = blockIdx.z;
  const bfloat *A0, *A1 = nullptr, *Wm;
  bfloat *Oh = nullptr, *Ol = nullptr;
  float scale = 1.f;
  bool split;
  if (z == 0) {
    A0 = xqh; A1 = xql; Wm = wqt; Oh = qmh; Ol = qml;
    scale = 0.18033688f;  // 1/sqrt(64) * log2(e), folded out of flash
    split = true;
  } else if (z == 1) {
    A0 = xkh; A1 = xkl; Wm = wkt; Oh = kmh; Ol = kml; split = true;
  } else {
    A0 = xvh; Wm = wvt; split = false;
  }

  const int t = threadIdx.x;
  const int w = t >> 6, lane = t & 63;
  const int quad = lane >> 4, l16 = lane & 15;
  const int wm = w >> 1, wn = w & 1;
  const int m0 = blockIdx.y * 128, n0 = blockIdx.x * 128;

  f32x4 acc[4][4] = {};

  const int sr = t >> 2;
  const int sc = (t & 3) * 8;

  const bfloat* pA0a = A0 + (size_t)(m0 + sr) * K + sc;
  const bfloat* pA0b = A0 + (size_t)(m0 + 64 + sr) * K + sc;
  const bfloat* pA1a = split ? A1 + (size_t)(m0 + sr) * K + sc : nullptr;
  const bfloat* pA1b = split ? A1 + (size_t)(m0 + 64 + sr) * K + sc : nullptr;
  const bfloat* pWa = Wm + (size_t)(n0 + sr) * K + sc;
  const bfloat* pWb = Wm + (size_t)(n0 + 64 + sr) * K + sc;

  for (int kk = 0; kk < K; kk += 32) {
    gl_lds16(pA0a + kk, As0 + w * 512);
    gl_lds16(pA0b + kk, As0 + 2048 + w * 512);
    if (split) {
      gl_lds16(pA1a + kk, As1 + w * 512);
      gl_lds16(pA1b + kk, As1 + 2048 + w * 512);
    }
    gl_lds16(pWa + kk, Ws + w * 512);
    gl_lds16(pWb + kk, Ws + 2048 + w * 512);
    __syncthreads();

    bf16x8 bfrag[4], afrag[4];
#pragma unroll
    for (int nt = 0; nt < 4; nt++)
      bfrag[nt] = *(const bf16x8*)&Ws[(wn * 64 + nt * 16 + l16) * 32 + quad * 8];
#pragma unroll
    for (int mt = 0; mt < 4; mt++)
      afrag[mt] = *(const bf16x8*)&As0[(wm * 64 + mt * 16 + l16) * 32 + quad * 8];
#pragma unroll
    for (int mt = 0; mt < 4; mt++)
#pragma unroll
      for (int nt = 0; nt < 4; nt++)
        acc[mt][nt] = MFMA_BF16(afrag[mt], bfrag[nt], acc[mt][nt]);
    if (split) {
#pragma unroll
      for (int mt = 0; mt < 4; mt++)
        afrag[mt] = *(const bf16x8*)&As1[(wm * 64 + mt * 16 + l16) * 32 + quad * 8];
#pragma unroll
      for (int mt = 0; mt < 4; mt++)
#pragma unroll
        for (int nt = 0; nt < 4; nt++)
          acc[mt][nt] = MFMA_BF16(afrag[mt], bfrag[nt], acc[mt][nt]);
    }
    __syncthreads();
  }

#pragma unroll
  for (int mt = 0; mt < 4; mt++) {
#pragma unroll
    for (int nt = 0; nt < 4; nt++) {
      const int row = m0 + wm * 64 + mt * 16 + quad * 4;
      const int col = n0 + wn * 64 + nt * 16 + l16;
      if (split) {
#pragma unroll
        for (int rg = 0; rg < 4; rg++) {
          float vv = acc[mt][nt][rg] * scale;
          size_t idx = (size_t)(row + rg) * N + col;
          bfloat hh = (bfloat)vv;
          Oh[idx] = hh;
          Ol[idx] = (bfloat)(vv - (float)hh);
        }
      } else {
        // V^T write: 4 consecutive tokens at fixed feature col
        int bb = row >> 11, s = row & (S - 1);
        bf16x4 pk;
#pragma unroll
        for (int rg = 0; rg < 4; rg++) pk[rg] = (bfloat)acc[mt][nt][rg];
        *(bf16x4*)&vtr[(size_t)bb * D * S + (size_t)col * S + s] = pk;
      }
    }
  }
}

// -------- W_O GEMM: 128x64 tile, grid (16,32)=512 blocks = 2/CU, fp32 out --
__global__ __launch_bounds__(256) void gemm_wo(const bfloat* __restrict__ A,
                                               const bfloat* __restrict__ Wm,
                                               float* __restrict__ Cf) {
  constexpr int K = D;
  constexpr int N = D;
  __shared__ __align__(16) bfloat As[128 * 32];
  __shared__ __align__(16) bfloat Ws[64 * 32];

  const int t = threadIdx.x;
  const int w = t >> 6, lane = t & 63;
  const int quad = lane >> 4, l16 = lane & 15;
  const int wm = w >> 1, wn = w & 1;
  const int m0 = blockIdx.y * 128, n0 = blockIdx.x * 64;

  f32x4 acc[4][2] = {};

  const int sr = t >> 2;
  const int sc = (t & 3) * 8;
  const bfloat* pAa = A + (size_t)(m0 + sr) * K + sc;
  const bfloat* pAb = A + (size_t)(m0 + 64 + sr) * K + sc;
  const bfloat* pW = Wm + (size_t)(n0 + sr) * K + sc;

  for (int kk = 0; kk < K; kk += 32) {
    gl_lds16(pAa + kk, As + w * 512);
    gl_lds16(pAb + kk, As + 2048 + w * 512);
    gl_lds16(pW + kk, Ws + w * 512);
    __syncthreads();

    bf16x8 bfrag[2], afrag[4];
#pragma unroll
    for (int nt = 0; nt < 2; nt++)
      bfrag[nt] = *(const bf16x8*)&Ws[(wn * 32 + nt * 16 + l16) * 32 + quad * 8];
#pragma unroll
    for (int mt = 0; mt < 4; mt++)
      afrag[mt] = *(const bf16x8*)&As[(wm * 64 + mt * 16 + l16) * 32 + quad * 8];
#pragma unroll
    for (int mt = 0; mt < 4; mt++)
#pragma unroll
      for (int nt = 0; nt < 2; nt++)
        acc[mt][nt] = MFMA_BF16(afrag[mt], bfrag[nt], acc[mt][nt]);
    __syncthreads();
  }

#pragma unroll
  for (int mt = 0; mt < 4; mt++) {
#pragma unroll
    for (int nt = 0; nt < 2; nt++) {
      const int row = m0 + wm * 64 + mt * 16 + quad * 4;
      const int col = n0 + wn * 32 + nt * 16 + l16;
#pragma unroll
      for (int rg = 0; rg < 4; rg++) Cf[(size_t)(row + rg) * N + col] = acc[mt][nt][rg];
    }
  }
}

// ---------------- flash attention v5: transposed scores -------------------
// S^T = K*Q^T: each lane owns one query row (qrow = l16). Softmax is in-lane
// (15 fmax + 2 shfl_xor); P lands with 4 consecutive keys per lane -> b64
// LDS writes; PV computes O^T = V^T * P^T. 64 qrows/block, 4 blocks/CU.
__global__ __launch_bounds__(256) void flash_kernel(
    const bfloat* __restrict__ qh, const bfloat* __restrict__ ql,
    const bfloat* __restrict__ kh, const bfloat* __restrict__ kl,
    const bfloat* __restrict__ vt, bfloat* __restrict__ outp) {
  __shared__ __align__(16) bfloat Kh[64 * 64];
  __shared__ __align__(16) bfloat Kl[64 * 64];
  __shared__ __align__(16) bfloat Vt[64 * 64];
  __shared__ __align__(16) bfloat Pm[64 * 64];

  const int t = threadIdx.x;
  const int w = t >> 6, lane = t & 63;
  const int quad = lane >> 4, l16 = lane & 15;
  const int b = blockIdx.z, h = blockIdx.y;
  const int q0 = blockIdx.x * 64;
  const size_t base = (size_t)b * S * D + (size_t)h * DH;       // [b][s][n]
  const size_t vbase = (size_t)b * D * S + (size_t)h * DH * S;  // [b][n][s]

  const int ssr = lane >> 3;
  const int spc = lane & 7;

  bf16x8 ones;
#pragma unroll
  for (int j = 0; j < 8; j++) ones[j] = (bfloat)1.f;

  // ---- prologue: stage Q hi/lo through K buffers; B-frags to registers ----
#pragma unroll
  for (int g = 0; g < 2; g++) {
    int r = w * 16 + g * 8 + ssr;
    int c = spc ^ (r & 7);
    int lo = (w * 16 + g * 8) * 64;
    gl_lds16(qh + base + (size_t)(q0 + r) * D + c * 8, Kh + lo);
    gl_lds16(ql + base + (size_t)(q0 + r) * D + c * 8, Kl + lo);
  }
  __syncthreads();
  bf16x8 qhf[2], qlf[2];
  {
    int row = w * 16 + l16;
#pragma unroll
    for (int s2 = 0; s2 < 2; s2++) {
      qhf[s2] = *(const bf16x8*)&Kh[row * 64 + (((s2 * 4 + quad) ^ (l16 & 7)) * 8)];
      qlf[s2] = *(const bf16x8*)&Kl[row * 64 + (((s2 * 4 + quad) ^ (l16 & 7)) * 8)];
    }
  }
  __syncthreads();  // Q frag reads done before first K staging

  f32x4 Oa[4] = {};  // O^T: [dim-tile]; elem rg: dim=mt*16+quad*4+rg, qrow=l16
  f32x4 La = {};     // all regs equal: sum_k P (per qrow=l16)
  float m_i = -3.0e38f;

  for (int k0 = 0; k0 < S; k0 += 64) {
#pragma unroll
    for (int g = 0; g < 2; g++) {
      int r = w * 16 + g * 8 + ssr;
      int c = spc ^ (r & 7);
      int lo = (w * 16 + g * 8) * 64;
      gl_lds16(kh + base + (size_t)(k0 + r) * D + c * 8, Kh + lo);
      gl_lds16(kl + base + (size_t)(k0 + r) * D + c * 8, Kl + lo);
      gl_lds16(vt + vbase + (size_t)r * S + k0 + c * 8, Vt + lo);
    }
    __syncthreads();

    // S^T = Kh*Qh + Kl*Qh + Kh*Ql (pre-scaled, log2 domain)
    f32x4 sf[4];
#pragma unroll
    for (int mt = 0; mt < 4; mt++) {
      f32x4 a = {};
      int krow = mt * 16 + l16;
#pragma unroll
      for (int s2 = 0; s2 < 2; s2++) {
        bf16x8 bh = *(const bf16x8*)&Kh[krow * 64 + (((s2 * 4 + quad) ^ (l16 & 7)) * 8)];
        bf16x8 bl = *(const bf16x8*)&Kl[krow * 64 + (((s2 * 4 + quad) ^ (l16 & 7)) * 8)];
        a = MFMA_BF16(bh, qhf[s2], a);
        a = MFMA_BF16(bl, qhf[s2], a);
        a = MFMA_BF16(bh, qlf[s2], a);
      }
      sf[mt] = a;
    }

    // online softmax: lane-scalar state (qrow = l16)
    float mm = sf[0][0];
#pragma unroll
    for (int mt = 0; mt < 4; mt++)
#pragma unroll
      for (int rg = 0; rg < 4; rg++) mm = fmaxf(mm, sf[mt][rg]);
    mm = fmaxf(mm, __shfl_xor(mm, 16, 64));
    mm = fmaxf(mm, __shfl_xor(mm, 32, 64));
    float mnew = fmaxf(m_i, mm);
    float alpha = exp2f(m_i - mnew);
    m_i = mnew;
#pragma unroll
    for (int mt = 0; mt < 4; mt++)
#pragma unroll
      for (int rg = 0; rg < 4; rg++) sf[mt][rg] = exp2f(sf[mt][rg] - mnew);
#pragma unroll
    for (int mt = 0; mt < 4; mt++) Oa[mt] *= alpha;
    La *= alpha;

    // P write: 4 consecutive keys per lane -> b64, 16B-granule swizzle
#pragma unroll
    for (int mt = 0; mt < 4; mt++) {
      bf16x4 pk;
#pragma unroll
      for (int rg = 0; rg < 4; rg++) pk[rg] = (bfloat)sf[mt][rg];
      int g16 = (mt * 2 + (quad >> 1)) ^ (l16 & 7);
      *(bf16x4*)&Pm[(w * 16 + l16) * 64 + g16 * 8 + (quad & 1) * 4] = pk;
    }

    // O^T += V^T * P^T ; La += ones * P^T  (Pm rows wave-private: no barrier)
#pragma unroll
    for (int s2 = 0; s2 < 2; s2++) {
      bf16x8 pb = *(const bf16x8*)&Pm[(w * 16 + l16) * 64 +
                                      (((s2 * 4 + quad) ^ (l16 & 7)) * 8)];
#pragma unroll
      for (int mt = 0; mt < 4; mt++) {
        int vrow = mt * 16 + l16;
        bf16x8 va = *(const bf16x8*)&Vt[vrow * 64 + (((s2 * 4 + quad) ^ (l16 & 7)) * 8)];
        Oa[mt] = MFMA_BF16(va, pb, Oa[mt]);
      }
      La = MFMA_BF16(ones, pb, La);
    }
    __syncthreads();  // frag reads done before next iteration's staging
  }

  // epilogue: lane owns qrow=l16; 4 consecutive dims per (mt) -> b64 stores
  float inv = 1.0f / La[0];
  const int qrow = q0 + w * 16 + l16;
#pragma unroll
  for (int mt = 0; mt < 4; mt++) {
    bf16x4 ov;
#pragma unroll
    for (int rg = 0; rg < 4; rg++) ov[rg] = (bfloat)(Oa[mt][rg] * inv);
    *(bf16x4*)&outp[base + (size_t)qrow * D + mt * 16 + quad * 4] = ov;
  }
}

extern "C" void kernel_launch(void* const* d_in, const int* in_sizes, int n_in,
                              void* d_out, int out_size, void* d_ws, size_t ws_size,
                              hipStream_t stream) {
  const float* q_in = (const float*)d_in[0];
  const float* k_in = (const float*)d_in[1];
  const float* v_in = (const float*)d_in[2];
  const float* wq = (const float*)d_in[3];
  const float* wk = (const float*)d_in[4];
  const float* wv = (const float*)d_in[5];
  const float* wo = (const float*)d_in[6];
  float* outp = (float*)d_out;
  char* ws = (char*)d_ws;

  constexpr size_t WBYTES = (size_t)WMAT_N * 2;
  constexpr size_t XBYTES = (size_t)M * D * 2;
  size_t off = 0;
  double* sums = (double*)(ws + off); off += 256;
  bfloat* wqt = (bfloat*)(ws + off); off += WBYTES;
  bfloat* wkt = (bfloat*)(ws + off); off += WBYTES;
  bfloat* wvt = (bfloat*)(ws + off); off += WBYTES;
  bfloat* wot = (bfloat*)(ws + off); off += WBYTES;
  bfloat* xqh = (bfloat*)(ws + off); off += XBYTES;
  bfloat* xql = (bfloat*)(ws + off); off += XBYTES;
  bfloat* xkh = (bfloat*)(ws + off); off += XBYTES;
  bfloat* xkl = (bfloat*)(ws + off); off += XBYTES;
  bfloat* xvh = (bfloat*)(ws + off); off += XBYTES;
  bfloat* qmh = (bfloat*)(ws + off); off += XBYTES;
  bfloat* qml = (bfloat*)(ws + off); off += XBYTES;
  bfloat* kmh = (bfloat*)(ws + off); off += XBYTES;
  bfloat* kml = (bfloat*)(ws + off); off += XBYTES;
  bfloat* vtr = (bfloat*)(ws + off); off += XBYTES;  // V^T [B][D][S]
  bfloat* attn = xqh;  // dead after q projection

  hipMemsetAsync(sums, 0, 4 * sizeof(double), stream);
  absum_kernel<<<dim3(128, 4), 256, 0, stream>>>(wq, wk, wv, wo, sums);
  tern_kernel<<<dim3(128, 4), 256, 0, stream>>>(wq, wk, wv, wo, wqt, wkt, wvt, wot, sums);
  splitcvt3_kernel<<<dim3(512, 3), 256, 0, stream>>>(q_in, k_in, v_in, xqh, xql, xkh, xkl, xvh);
  qkv_gemm<<<dim3(D / 128, M / 128, 3), 256, 0, stream>>>(
      xqh, xql, xkh, xkl, xvh, wqt, wkt, wvt, qmh, qml, kmh, kml, vtr);
  flash_kernel<<<dim3(S / 64, H, B), 256, 0, stream>>>(qmh, qml, kmh, kml, vtr, attn);
  gemm_wo<<<dim3(D / 64, M / 128), 256, 0, stream>>>(attn, wot, outp);
}